// Round 2
// baseline (832.121 us; speedup 1.0000x reference)
//
#include <hip/hip_runtime.h>

#define N_NODES 100000
#define D 128
#define N_MESH 600000
#define N_WORLD 300000
#define BM 64          // nodes per block in MLP kernel
#define LDK 392        // padded leading dim of h tile (384 + 8) in bf16 elems
#define LDH 136        // padded leading dim of h1 tile (128 + 8)

typedef __attribute__((ext_vector_type(8))) short short8;
typedef __attribute__((ext_vector_type(4))) float f32x4;

// f32 -> bf16 round-to-nearest-even (finite inputs)
__device__ __forceinline__ unsigned short f2bf(float f) {
    unsigned u = __builtin_bit_cast(unsigned, f);
    u += 0x7fffu + ((u >> 16) & 1u);
    return (unsigned short)(u >> 16);
}

// ---------------- histogram of dst ----------------------------------------
__global__ __launch_bounds__(256) void hist_kernel(
        const int* __restrict__ dst, int E, int* __restrict__ cnt) {
    int i = blockIdx.x * 256 + threadIdx.x;
    if (i < E) atomicAdd(&cnt[dst[i]], 1);
}

// ---------------- single-block exclusive scan of N_NODES counts -----------
__global__ __launch_bounds__(1024) void scan_kernel(
        const int* __restrict__ cnt, int* __restrict__ offs, int* __restrict__ cursor) {
    const int n = N_NODES;
    const int tid = threadIdx.x;
    const int per = (n + 1023) / 1024;          // 98
    int lo = tid * per, hi = lo + per < n ? lo + per : n;
    int s = 0;
    for (int i = lo; i < hi; i++) s += cnt[i];
    __shared__ int sums[1024];
    sums[tid] = s;
    __syncthreads();
    for (int d = 1; d < 1024; d <<= 1) {
        int v = (tid >= d) ? sums[tid - d] : 0;
        __syncthreads();
        sums[tid] += v;
        __syncthreads();
    }
    int run = sums[tid] - s;                    // exclusive base for this chunk
    for (int i = lo; i < hi; i++) {
        offs[i] = run; cursor[i] = run; run += cnt[i];
    }
    if (tid == 1023) offs[n] = run;             // grand total
}

// ---------------- build permutation (counting-sort placement) -------------
__global__ __launch_bounds__(256) void build_perm(
        const int* __restrict__ dst, int E, int* __restrict__ cursor,
        int* __restrict__ perm) {
    int i = blockIdx.x * 256 + threadIdx.x;
    if (i < E) {
        int slot = atomicAdd(&cursor[dst[i]], 1);
        perm[slot] = i;
    }
}

// ---------------- gather-reduce: agg[n] = mean of attr rows ---------------
__global__ __launch_bounds__(256) void aggregate_kernel(
        const float* __restrict__ attr, const int* __restrict__ perm,
        const int* __restrict__ offs, float* __restrict__ agg) {
    int node = blockIdx.x * 4 + (threadIdx.x >> 6);
    if (node >= N_NODES) return;
    int l = threadIdx.x & 63;
    int beg = offs[node], end = offs[node + 1];
    float sx = 0.f, sy = 0.f;
    int j = beg;
    if (j < end) {
        int e = perm[j];
        float2 v = *reinterpret_cast<const float2*>(&attr[(size_t)e * D + l * 2]);
        for (++j; j < end; ++j) {
            int e2 = perm[j];
            float2 v2 = *reinterpret_cast<const float2*>(&attr[(size_t)e2 * D + l * 2]);
            sx += v.x; sy += v.y;
            v = v2;
        }
        sx += v.x; sy += v.y;
    }
    int c = end - beg;
    float inv = 1.0f / (float)(c > 1 ? c : 1);
    float2 r; r.x = sx * inv; r.y = sy * inv;
    *reinterpret_cast<float2*>(&agg[(size_t)node * D + l * 2]) = r;
}

// ---------------- weight prep: transpose + f32->bf16 ----------------------
__global__ __launch_bounds__(256) void prep_weights(
        const float* __restrict__ W1, const float* __restrict__ W2,
        unsigned short* __restrict__ Wt1, unsigned short* __restrict__ Wt2) {
    int idx = blockIdx.x * 256 + threadIdx.x;
    if (idx < 384 * D) {
        int n = idx / 384, k = idx % 384;
        Wt1[n * 384 + k] = f2bf(W1[k * D + n]);      // Wt1[n][k] = W1[k][n]
    } else if (idx < 384 * D + D * D) {
        int i2 = idx - 384 * D;
        int n = i2 / D, k = i2 % D;
        Wt2[n * D + k] = f2bf(W2[k * D + n]);
    }
}

// ---------------- fused MLP per 64-node tile ------------------------------
__global__ __launch_bounds__(256) void mlp_kernel(
        const float* __restrict__ x,
        const float* __restrict__ mesh_agg, const float* __restrict__ world_agg,
        const unsigned short* __restrict__ Wt1, const unsigned short* __restrict__ Wt2,
        const float* __restrict__ b1, const float* __restrict__ b2,
        const float* __restrict__ gamma, const float* __restrict__ beta,
        float* __restrict__ out) {
    __shared__ __align__(16) short h_lds[BM * LDK];   // 50176 B, reused for h1
    const int tid = threadIdx.x;
    const int block0 = blockIdx.x * BM;

    // ---- Phase A: stage h = [x | mesh_agg | world_agg] as bf16 -----------
    for (int idx = tid; idx < BM * 32; idx += 256) {
        int row = idx >> 5, c4 = (idx & 31) * 4;
        int node = block0 + row;
        float4 v = {0.f, 0.f, 0.f, 0.f};
        if (node < N_NODES) v = *reinterpret_cast<const float4*>(&x[(size_t)node * D + c4]);
        ushort4 pack = {f2bf(v.x), f2bf(v.y), f2bf(v.z), f2bf(v.w)};
        *reinterpret_cast<ushort4*>(&h_lds[row * LDK + c4]) = pack;
    }
    for (int idx = tid; idx < BM * 32; idx += 256) {
        int row = idx >> 5, c4 = (idx & 31) * 4;
        int node = block0 + row;
        float4 v = {0.f, 0.f, 0.f, 0.f};
        if (node < N_NODES) v = *reinterpret_cast<const float4*>(&mesh_agg[(size_t)node * D + c4]);
        ushort4 pack = {f2bf(v.x), f2bf(v.y), f2bf(v.z), f2bf(v.w)};
        *reinterpret_cast<ushort4*>(&h_lds[row * LDK + 128 + c4]) = pack;
    }
    for (int idx = tid; idx < BM * 32; idx += 256) {
        int row = idx >> 5, c4 = (idx & 31) * 4;
        int node = block0 + row;
        float4 v = {0.f, 0.f, 0.f, 0.f};
        if (node < N_NODES) v = *reinterpret_cast<const float4*>(&world_agg[(size_t)node * D + c4]);
        ushort4 pack = {f2bf(v.x), f2bf(v.y), f2bf(v.z), f2bf(v.w)};
        *reinterpret_cast<ushort4*>(&h_lds[row * LDK + 256 + c4]) = pack;
    }
    __syncthreads();

    // ---- Phase B: GEMM1  h[64x384] @ W1[384x128]  (wave w owns 16 rows) --
    const int w = tid >> 6, l = tid & 63;
    const int lm = l & 15, lg = l >> 4;
    f32x4 acc[8];
    #pragma unroll
    for (int nt = 0; nt < 8; nt++) {
        float bv = b1[nt * 16 + lm];
        acc[nt] = (f32x4){bv, bv, bv, bv};
    }
    {
        const short* arow = &h_lds[(w * 16 + lm) * LDK + lg * 8];
        for (int ks = 0; ks < 12; ks++) {
            short8 a = *reinterpret_cast<const short8*>(arow + ks * 32);
            #pragma unroll
            for (int nt = 0; nt < 8; nt++) {
                short8 b = *reinterpret_cast<const short8*>(
                    &Wt1[(size_t)(nt * 16 + lm) * 384 + ks * 32 + lg * 8]);
                acc[nt] = __builtin_amdgcn_mfma_f32_16x16x32_bf16(a, b, acc[nt], 0, 0, 0);
            }
        }
    }
    __syncthreads();   // all waves finished reading h_lds

    // ---- Phase C: ReLU -> bf16 -> h1 in LDS (reuse h_lds) ----------------
    // C/D layout: col = nt*16 + (lane&15), row = (lane>>4)*4 + reg
    #pragma unroll
    for (int nt = 0; nt < 8; nt++) {
        #pragma unroll
        for (int r = 0; r < 4; r++) {
            float v = acc[nt][r] > 0.f ? acc[nt][r] : 0.f;
            int row = w * 16 + lg * 4 + r;
            h_lds[row * LDH + nt * 16 + lm] = (short)f2bf(v);
        }
    }
    __syncthreads();

    // ---- Phase D: GEMM2  h1[64x128] @ W2[128x128] ------------------------
    f32x4 acc2[8];
    #pragma unroll
    for (int nt = 0; nt < 8; nt++) {
        float bv = b2[nt * 16 + lm];
        acc2[nt] = (f32x4){bv, bv, bv, bv};
    }
    {
        const short* a2row = &h_lds[(w * 16 + lm) * LDH + lg * 8];
        for (int ks = 0; ks < 4; ks++) {
            short8 a = *reinterpret_cast<const short8*>(a2row + ks * 32);
            #pragma unroll
            for (int nt = 0; nt < 8; nt++) {
                short8 b = *reinterpret_cast<const short8*>(
                    &Wt2[(size_t)(nt * 16 + lm) * D + ks * 32 + lg * 8]);
                acc2[nt] = __builtin_amdgcn_mfma_f32_16x16x32_bf16(a, b, acc2[nt], 0, 0, 0);
            }
        }
    }

    // ---- Phase E: LayerNorm (in-register, 16-lane reductions) + residual -
    float gam[8], bet[8];
    #pragma unroll
    for (int nt = 0; nt < 8; nt++) {
        gam[nt] = gamma[nt * 16 + lm];
        bet[nt] = beta[nt * 16 + lm];
    }
    #pragma unroll
    for (int r = 0; r < 4; r++) {
        float s = 0.f, ss = 0.f;
        #pragma unroll
        for (int nt = 0; nt < 8; nt++) { float v = acc2[nt][r]; s += v; ss += v * v; }
        #pragma unroll
        for (int m = 1; m < 16; m <<= 1) {
            s  += __shfl_xor(s, m, 64);
            ss += __shfl_xor(ss, m, 64);
        }
        float mean = s * (1.0f / 128.0f);
        float var  = ss * (1.0f / 128.0f) - mean * mean;
        float rstd = rsqrtf(var + 1e-5f);
        int node = block0 + w * 16 + lg * 4 + r;
        if (node < N_NODES) {
            #pragma unroll
            for (int nt = 0; nt < 8; nt++) {
                int col = nt * 16 + lm;
                float v = (acc2[nt][r] - mean) * rstd * gam[nt] + bet[nt];
                out[(size_t)node * D + col] = x[(size_t)node * D + col] + v;
            }
        }
    }
}

extern "C" void kernel_launch(void* const* d_in, const int* in_sizes, int n_in,
                              void* d_out, int out_size, void* d_ws, size_t ws_size,
                              hipStream_t stream) {
    const float* x          = (const float*)d_in[0];
    const float* mesh_attr  = (const float*)d_in[1];
    const float* world_attr = (const float*)d_in[2];
    const int*   mesh_dst   = (const int*)d_in[3];
    const int*   world_dst  = (const int*)d_in[4];
    const float* W1         = (const float*)d_in[5];
    const float* b1         = (const float*)d_in[6];
    const float* W2         = (const float*)d_in[7];
    const float* b2         = (const float*)d_in[8];
    const float* gamma      = (const float*)d_in[9];
    const float* beta       = (const float*)d_in[10];
    float* out = (float*)d_out;

    char* ws = (char*)d_ws;
    size_t off = 0;
    float* world_agg = (float*)(ws + off); off += (size_t)N_NODES * D * 4;   // 51.2 MB
    int* mesh_cnt   = (int*)(ws + off); off += (size_t)N_NODES * 4;
    int* world_cnt  = (int*)(ws + off); off += (size_t)N_NODES * 4;
    size_t cnt_off = (size_t)N_NODES * D * 4;          // start of the zeroed region
    size_t cnt_bytes = (size_t)N_NODES * 4 * 2;
    int* mesh_cur   = (int*)(ws + off); off += (size_t)N_NODES * 4;
    int* world_cur  = (int*)(ws + off); off += (size_t)N_NODES * 4;
    int* mesh_perm  = (int*)(ws + off); off += (size_t)N_MESH * 4;
    int* world_perm = (int*)(ws + off); off += (size_t)N_WORLD * 4;
    int* mesh_offs  = (int*)(ws + off); off += (size_t)(N_NODES + 1) * 4;
    int* world_offs = (int*)(ws + off); off += (size_t)(N_NODES + 1) * 4;
    off = (off + 15) & ~(size_t)15;
    unsigned short* Wt1 = (unsigned short*)(ws + off); off += (size_t)384 * D * 2;
    unsigned short* Wt2 = (unsigned short*)(ws + off); off += (size_t)D * D * 2;

    // mesh_agg aliases d_out: each MLP block reads its own agg rows (phase A)
    // strictly before writing the same out rows (phase E).
    float* mesh_agg = out;

    hipMemsetAsync(ws + cnt_off, 0, cnt_bytes, stream);
    hist_kernel<<<(N_MESH  + 255) / 256, 256, 0, stream>>>(mesh_dst,  N_MESH,  mesh_cnt);
    hist_kernel<<<(N_WORLD + 255) / 256, 256, 0, stream>>>(world_dst, N_WORLD, world_cnt);
    scan_kernel<<<1, 1024, 0, stream>>>(mesh_cnt,  mesh_offs,  mesh_cur);
    scan_kernel<<<1, 1024, 0, stream>>>(world_cnt, world_offs, world_cur);
    build_perm<<<(N_MESH  + 255) / 256, 256, 0, stream>>>(mesh_dst,  N_MESH,  mesh_cur,  mesh_perm);
    build_perm<<<(N_WORLD + 255) / 256, 256, 0, stream>>>(world_dst, N_WORLD, world_cur, world_perm);
    prep_weights<<<(384 * D + D * D + 255) / 256, 256, 0, stream>>>(W1, W2, Wt1, Wt2);
    aggregate_kernel<<<(N_NODES + 3) / 4, 256, 0, stream>>>(mesh_attr,  mesh_perm,  mesh_offs,  mesh_agg);
    aggregate_kernel<<<(N_NODES + 3) / 4, 256, 0, stream>>>(world_attr, world_perm, world_offs, world_agg);
    mlp_kernel<<<(N_NODES + BM - 1) / BM, 256, 0, stream>>>(
        x, mesh_agg, world_agg, Wt1, Wt2, b1, b2, gamma, beta, out);
}

// Round 3
// 394.509 us; speedup vs baseline: 2.1093x; 2.1093x over previous
//
#include <hip/hip_runtime.h>

#define N_NODES 100000
#define D 128
#define N_MESH 600000
#define N_WORLD 300000
#define BM 64          // nodes per block in MLP kernel
#define LDK 392        // padded leading dim of h tile (384 + 8) in bf16 elems
#define LDH 136        // padded leading dim of h1 tile (128 + 8)
#define SCAN_B 1024
#define SCAN_GRID ((N_NODES + SCAN_B - 1) / SCAN_B)   // 98

typedef __attribute__((ext_vector_type(8))) short short8;
typedef __attribute__((ext_vector_type(4))) float f32x4;

// f32 -> bf16 round-to-nearest-even (finite inputs)
__device__ __forceinline__ unsigned short f2bf(float f) {
    unsigned u = __builtin_bit_cast(unsigned, f);
    u += 0x7fffu + ((u >> 16) & 1u);
    return (unsigned short)(u >> 16);
}

// ---------------- histogram of dst ----------------------------------------
__global__ __launch_bounds__(256) void hist_kernel(
        const int* __restrict__ dst, int E, int* __restrict__ cnt) {
    int i = blockIdx.x * 256 + threadIdx.x;
    if (i < E) atomicAdd(&cnt[dst[i]], 1);
}

// ---------------- multi-block scan, pass 1: per-block exclusive scan ------
// grid (SCAN_GRID, 2): y=0 mesh, y=1 world. Writes local exclusive scan into
// offs, per-block totals into bsums[y*128 + bx].
__global__ __launch_bounds__(1024) void scan_local(
        const int* __restrict__ cntM, const int* __restrict__ cntW,
        int* __restrict__ offsM, int* __restrict__ offsW,
        int* __restrict__ bsums) {
    const int* cnt = blockIdx.y ? cntW : cntM;
    int* offs = blockIdx.y ? offsW : offsM;
    __shared__ int tmp[SCAN_B];
    int g = blockIdx.x * SCAN_B + threadIdx.x;
    int v = (g < N_NODES) ? cnt[g] : 0;
    tmp[threadIdx.x] = v;
    __syncthreads();
    for (int d = 1; d < SCAN_B; d <<= 1) {
        int t = (threadIdx.x >= d) ? tmp[threadIdx.x - d] : 0;
        __syncthreads();
        tmp[threadIdx.x] += t;
        __syncthreads();
    }
    if (g < N_NODES) offs[g] = tmp[threadIdx.x] - v;   // exclusive within block
    if (threadIdx.x == SCAN_B - 1) bsums[blockIdx.y * 128 + blockIdx.x] = tmp[SCAN_B - 1];
}

// ---------------- pass 2: exclusive scan of block sums (grid=2 blocks) ----
__global__ __launch_bounds__(128) void scan_mid(int* __restrict__ bsums) {
    __shared__ int tmp[128];
    int* b = bsums + blockIdx.x * 128;
    int v = (threadIdx.x < SCAN_GRID) ? b[threadIdx.x] : 0;
    tmp[threadIdx.x] = v;
    __syncthreads();
    for (int d = 1; d < 128; d <<= 1) {
        int t = (threadIdx.x >= d) ? tmp[threadIdx.x - d] : 0;
        __syncthreads();
        tmp[threadIdx.x] += t;
        __syncthreads();
    }
    if (threadIdx.x < SCAN_GRID) b[threadIdx.x] = tmp[threadIdx.x] - v;  // exclusive
}

// ---------------- pass 3: add block base, emit offs + cursor --------------
__global__ __launch_bounds__(1024) void scan_finalize(
        int* __restrict__ offsM, int* __restrict__ offsW,
        int* __restrict__ curM, int* __restrict__ curW,
        const int* __restrict__ bsums) {
    int* offs = blockIdx.y ? offsW : offsM;
    int* cur  = blockIdx.y ? curW  : curM;
    int g = blockIdx.x * SCAN_B + threadIdx.x;
    if (g < N_NODES) {
        int o = offs[g] + bsums[blockIdx.y * 128 + blockIdx.x];
        offs[g] = o;
        cur[g] = o;
    }
    if (g == 0) offs[N_NODES] = blockIdx.y ? N_WORLD : N_MESH;
}

// ---------------- build permutation (counting-sort placement) -------------
__global__ __launch_bounds__(256) void build_perm(
        const int* __restrict__ dst, int E, int* __restrict__ cursor,
        int* __restrict__ perm) {
    int i = blockIdx.x * 256 + threadIdx.x;
    if (i < E) {
        int slot = atomicAdd(&cursor[dst[i]], 1);
        perm[slot] = i;
    }
}

// ---------------- gather-reduce: agg[n] = mean of attr rows ---------------
__global__ __launch_bounds__(256) void aggregate_kernel(
        const float* __restrict__ attr, const int* __restrict__ perm,
        const int* __restrict__ offs, float* __restrict__ agg) {
    int node = blockIdx.x * 4 + (threadIdx.x >> 6);
    if (node >= N_NODES) return;
    int l = threadIdx.x & 63;
    int beg = offs[node], end = offs[node + 1];
    float sx = 0.f, sy = 0.f;
    int j = beg;
    if (j < end) {
        int e = perm[j];
        float2 v = *reinterpret_cast<const float2*>(&attr[(size_t)e * D + l * 2]);
        for (++j; j < end; ++j) {
            int e2 = perm[j];
            float2 v2 = *reinterpret_cast<const float2*>(&attr[(size_t)e2 * D + l * 2]);
            sx += v.x; sy += v.y;
            v = v2;
        }
        sx += v.x; sy += v.y;
    }
    int c = end - beg;
    float inv = 1.0f / (float)(c > 1 ? c : 1);
    float2 r; r.x = sx * inv; r.y = sy * inv;
    *reinterpret_cast<float2*>(&agg[(size_t)node * D + l * 2]) = r;
}

// ---------------- weight prep: transpose + f32->bf16 ----------------------
__global__ __launch_bounds__(256) void prep_weights(
        const float* __restrict__ W1, const float* __restrict__ W2,
        unsigned short* __restrict__ Wt1, unsigned short* __restrict__ Wt2) {
    int idx = blockIdx.x * 256 + threadIdx.x;
    if (idx < 384 * D) {
        int n = idx / 384, k = idx % 384;
        Wt1[n * 384 + k] = f2bf(W1[k * D + n]);      // Wt1[n][k] = W1[k][n]
    } else if (idx < 384 * D + D * D) {
        int i2 = idx - 384 * D;
        int n = i2 / D, k = i2 % D;
        Wt2[n * D + k] = f2bf(W2[k * D + n]);
    }
}

// ---------------- fused MLP per 64-node tile ------------------------------
__global__ __launch_bounds__(256) void mlp_kernel(
        const float* __restrict__ x,
        const float* __restrict__ mesh_agg, const float* __restrict__ world_agg,
        const unsigned short* __restrict__ Wt1, const unsigned short* __restrict__ Wt2,
        const float* __restrict__ b1, const float* __restrict__ b2,
        const float* __restrict__ gamma, const float* __restrict__ beta,
        float* __restrict__ out) {
    __shared__ __align__(16) short h_lds[BM * LDK];   // 50176 B, reused for h1
    const int tid = threadIdx.x;
    const int block0 = blockIdx.x * BM;

    // ---- Phase A: stage h = [x | mesh_agg | world_agg] as bf16 -----------
    for (int idx = tid; idx < BM * 32; idx += 256) {
        int row = idx >> 5, c4 = (idx & 31) * 4;
        int node = block0 + row;
        float4 v = {0.f, 0.f, 0.f, 0.f};
        if (node < N_NODES) v = *reinterpret_cast<const float4*>(&x[(size_t)node * D + c4]);
        ushort4 pack = {f2bf(v.x), f2bf(v.y), f2bf(v.z), f2bf(v.w)};
        *reinterpret_cast<ushort4*>(&h_lds[row * LDK + c4]) = pack;
    }
    for (int idx = tid; idx < BM * 32; idx += 256) {
        int row = idx >> 5, c4 = (idx & 31) * 4;
        int node = block0 + row;
        float4 v = {0.f, 0.f, 0.f, 0.f};
        if (node < N_NODES) v = *reinterpret_cast<const float4*>(&mesh_agg[(size_t)node * D + c4]);
        ushort4 pack = {f2bf(v.x), f2bf(v.y), f2bf(v.z), f2bf(v.w)};
        *reinterpret_cast<ushort4*>(&h_lds[row * LDK + 128 + c4]) = pack;
    }
    for (int idx = tid; idx < BM * 32; idx += 256) {
        int row = idx >> 5, c4 = (idx & 31) * 4;
        int node = block0 + row;
        float4 v = {0.f, 0.f, 0.f, 0.f};
        if (node < N_NODES) v = *reinterpret_cast<const float4*>(&world_agg[(size_t)node * D + c4]);
        ushort4 pack = {f2bf(v.x), f2bf(v.y), f2bf(v.z), f2bf(v.w)};
        *reinterpret_cast<ushort4*>(&h_lds[row * LDK + 256 + c4]) = pack;
    }
    __syncthreads();

    // ---- Phase B: GEMM1  h[64x384] @ W1[384x128]  (wave w owns 16 rows) --
    const int w = tid >> 6, l = tid & 63;
    const int lm = l & 15, lg = l >> 4;
    f32x4 acc[8];
    #pragma unroll
    for (int nt = 0; nt < 8; nt++) {
        float bv = b1[nt * 16 + lm];
        acc[nt] = (f32x4){bv, bv, bv, bv};
    }
    {
        const short* arow = &h_lds[(w * 16 + lm) * LDK + lg * 8];
        for (int ks = 0; ks < 12; ks++) {
            short8 a = *reinterpret_cast<const short8*>(arow + ks * 32);
            #pragma unroll
            for (int nt = 0; nt < 8; nt++) {
                short8 b = *reinterpret_cast<const short8*>(
                    &Wt1[(size_t)(nt * 16 + lm) * 384 + ks * 32 + lg * 8]);
                acc[nt] = __builtin_amdgcn_mfma_f32_16x16x32_bf16(a, b, acc[nt], 0, 0, 0);
            }
        }
    }
    __syncthreads();   // all waves finished reading h_lds

    // ---- Phase C: ReLU -> bf16 -> h1 in LDS (reuse h_lds) ----------------
    // C/D layout: col = nt*16 + (lane&15), row = (lane>>4)*4 + reg
    #pragma unroll
    for (int nt = 0; nt < 8; nt++) {
        #pragma unroll
        for (int r = 0; r < 4; r++) {
            float v = acc[nt][r] > 0.f ? acc[nt][r] : 0.f;
            int row = w * 16 + lg * 4 + r;
            h_lds[row * LDH + nt * 16 + lm] = (short)f2bf(v);
        }
    }
    __syncthreads();

    // ---- Phase D: GEMM2  h1[64x128] @ W2[128x128] ------------------------
    f32x4 acc2[8];
    #pragma unroll
    for (int nt = 0; nt < 8; nt++) {
        float bv = b2[nt * 16 + lm];
        acc2[nt] = (f32x4){bv, bv, bv, bv};
    }
    {
        const short* a2row = &h_lds[(w * 16 + lm) * LDH + lg * 8];
        for (int ks = 0; ks < 4; ks++) {
            short8 a = *reinterpret_cast<const short8*>(a2row + ks * 32);
            #pragma unroll
            for (int nt = 0; nt < 8; nt++) {
                short8 b = *reinterpret_cast<const short8*>(
                    &Wt2[(size_t)(nt * 16 + lm) * D + ks * 32 + lg * 8]);
                acc2[nt] = __builtin_amdgcn_mfma_f32_16x16x32_bf16(a, b, acc2[nt], 0, 0, 0);
            }
        }
    }

    // ---- Phase E: LayerNorm (in-register, 16-lane reductions) + residual -
    float gam[8], bet[8];
    #pragma unroll
    for (int nt = 0; nt < 8; nt++) {
        gam[nt] = gamma[nt * 16 + lm];
        bet[nt] = beta[nt * 16 + lm];
    }
    #pragma unroll
    for (int r = 0; r < 4; r++) {
        float s = 0.f, ss = 0.f;
        #pragma unroll
        for (int nt = 0; nt < 8; nt++) { float v = acc2[nt][r]; s += v; ss += v * v; }
        #pragma unroll
        for (int m = 1; m < 16; m <<= 1) {
            s  += __shfl_xor(s, m, 64);
            ss += __shfl_xor(ss, m, 64);
        }
        float mean = s * (1.0f / 128.0f);
        float var  = ss * (1.0f / 128.0f) - mean * mean;
        float rstd = rsqrtf(var + 1e-5f);
        int node = block0 + w * 16 + lg * 4 + r;
        if (node < N_NODES) {
            #pragma unroll
            for (int nt = 0; nt < 8; nt++) {
                int col = nt * 16 + lm;
                float v = (acc2[nt][r] - mean) * rstd * gam[nt] + bet[nt];
                out[(size_t)node * D + col] = x[(size_t)node * D + col] + v;
            }
        }
    }
}

extern "C" void kernel_launch(void* const* d_in, const int* in_sizes, int n_in,
                              void* d_out, int out_size, void* d_ws, size_t ws_size,
                              hipStream_t stream) {
    const float* x          = (const float*)d_in[0];
    const float* mesh_attr  = (const float*)d_in[1];
    const float* world_attr = (const float*)d_in[2];
    const int*   mesh_dst   = (const int*)d_in[3];
    const int*   world_dst  = (const int*)d_in[4];
    const float* W1         = (const float*)d_in[5];
    const float* b1         = (const float*)d_in[6];
    const float* W2         = (const float*)d_in[7];
    const float* b2         = (const float*)d_in[8];
    const float* gamma      = (const float*)d_in[9];
    const float* beta       = (const float*)d_in[10];
    float* out = (float*)d_out;

    char* ws = (char*)d_ws;
    size_t off = 0;
    float* world_agg = (float*)(ws + off); off += (size_t)N_NODES * D * 4;   // 51.2 MB
    int* mesh_cnt   = (int*)(ws + off); off += (size_t)N_NODES * 4;
    int* world_cnt  = (int*)(ws + off); off += (size_t)N_NODES * 4;
    size_t cnt_off = (size_t)N_NODES * D * 4;          // start of the zeroed region
    size_t cnt_bytes = (size_t)N_NODES * 4 * 2;
    int* mesh_cur   = (int*)(ws + off); off += (size_t)N_NODES * 4;
    int* world_cur  = (int*)(ws + off); off += (size_t)N_NODES * 4;
    int* mesh_perm  = (int*)(ws + off); off += (size_t)N_MESH * 4;
    int* world_perm = (int*)(ws + off); off += (size_t)N_WORLD * 4;
    int* mesh_offs  = (int*)(ws + off); off += (size_t)(N_NODES + 1) * 4;
    int* world_offs = (int*)(ws + off); off += (size_t)(N_NODES + 1) * 4;
    int* bsums      = (int*)(ws + off); off += (size_t)256 * 4;   // [2][128]
    off = (off + 15) & ~(size_t)15;
    unsigned short* Wt1 = (unsigned short*)(ws + off); off += (size_t)384 * D * 2;
    unsigned short* Wt2 = (unsigned short*)(ws + off); off += (size_t)D * D * 2;

    // mesh_agg aliases d_out: each MLP block reads its own agg rows (phase A)
    // strictly before writing the same out rows (phase E).
    float* mesh_agg = out;

    hipMemsetAsync(ws + cnt_off, 0, cnt_bytes, stream);
    hist_kernel<<<(N_MESH  + 255) / 256, 256, 0, stream>>>(mesh_dst,  N_MESH,  mesh_cnt);
    hist_kernel<<<(N_WORLD + 255) / 256, 256, 0, stream>>>(world_dst, N_WORLD, world_cnt);
    {
        dim3 g1(SCAN_GRID, 2);
        scan_local<<<g1, SCAN_B, 0, stream>>>(mesh_cnt, world_cnt, mesh_offs, world_offs, bsums);
        scan_mid<<<2, 128, 0, stream>>>(bsums);
        scan_finalize<<<g1, SCAN_B, 0, stream>>>(mesh_offs, world_offs, mesh_cur, world_cur, bsums);
    }
    build_perm<<<(N_MESH  + 255) / 256, 256, 0, stream>>>(mesh_dst,  N_MESH,  mesh_cur,  mesh_perm);
    build_perm<<<(N_WORLD + 255) / 256, 256, 0, stream>>>(world_dst, N_WORLD, world_cur, world_perm);
    prep_weights<<<(384 * D + D * D + 255) / 256, 256, 0, stream>>>(W1, W2, Wt1, Wt2);
    aggregate_kernel<<<(N_NODES + 3) / 4, 256, 0, stream>>>(mesh_attr,  mesh_perm,  mesh_offs,  mesh_agg);
    aggregate_kernel<<<(N_NODES + 3) / 4, 256, 0, stream>>>(world_attr, world_perm, world_offs, world_agg);
    mlp_kernel<<<(N_NODES + BM - 1) / BM, 256, 0, stream>>>(
        x, mesh_agg, world_agg, Wt1, Wt2, b1, b2, gamma, beta, out);
}

// Round 4
// 393.463 us; speedup vs baseline: 2.1149x; 1.0027x over previous
//
#include <hip/hip_runtime.h>

#define N_NODES 100000
#define D 128
#define N_MESH 600000
#define N_WORLD 300000
#define BM 64          // nodes per block in MLP kernel
#define LDK 392        // padded leading dim of h tile (384 + 8) in bf16 elems
#define LDH 136        // padded leading dim of h1 tile (128 + 8)
#define SCAN_B 1024
#define SCAN_GRID ((N_NODES + SCAN_B - 1) / SCAN_B)   // 98

typedef __attribute__((ext_vector_type(8))) short short8;
typedef __attribute__((ext_vector_type(4))) float f32x4;

// f32 -> bf16 round-to-nearest-even (finite inputs)
__device__ __forceinline__ unsigned short f2bf(float f) {
    unsigned u = __builtin_bit_cast(unsigned, f);
    u += 0x7fffu + ((u >> 16) & 1u);
    return (unsigned short)(u >> 16);
}

// ---------------- zero the count arrays (replaces pathological memset) ----
__global__ __launch_bounds__(256) void zero_counts(int* __restrict__ p, int n) {
    int i = blockIdx.x * 256 + threadIdx.x;
    if (i < n) p[i] = 0;
}

// ---------------- histogram of dst ----------------------------------------
__global__ __launch_bounds__(256) void hist_kernel(
        const int* __restrict__ dst, int E, int* __restrict__ cnt) {
    int i = blockIdx.x * 256 + threadIdx.x;
    if (i < E) atomicAdd(&cnt[dst[i]], 1);
}

// ---------------- multi-block scan, pass 1: per-block exclusive scan ------
__global__ __launch_bounds__(1024) void scan_local(
        const int* __restrict__ cntM, const int* __restrict__ cntW,
        int* __restrict__ offsM, int* __restrict__ offsW,
        int* __restrict__ bsums) {
    const int* cnt = blockIdx.y ? cntW : cntM;
    int* offs = blockIdx.y ? offsW : offsM;
    __shared__ int tmp[SCAN_B];
    int g = blockIdx.x * SCAN_B + threadIdx.x;
    int v = (g < N_NODES) ? cnt[g] : 0;
    tmp[threadIdx.x] = v;
    __syncthreads();
    for (int d = 1; d < SCAN_B; d <<= 1) {
        int t = (threadIdx.x >= d) ? tmp[threadIdx.x - d] : 0;
        __syncthreads();
        tmp[threadIdx.x] += t;
        __syncthreads();
    }
    if (g < N_NODES) offs[g] = tmp[threadIdx.x] - v;   // exclusive within block
    if (threadIdx.x == SCAN_B - 1) bsums[blockIdx.y * 128 + blockIdx.x] = tmp[SCAN_B - 1];
}

// ---------------- pass 2: exclusive scan of block sums (grid=2 blocks) ----
__global__ __launch_bounds__(128) void scan_mid(int* __restrict__ bsums) {
    __shared__ int tmp[128];
    int* b = bsums + blockIdx.x * 128;
    int v = (threadIdx.x < SCAN_GRID) ? b[threadIdx.x] : 0;
    tmp[threadIdx.x] = v;
    __syncthreads();
    for (int d = 1; d < 128; d <<= 1) {
        int t = (threadIdx.x >= d) ? tmp[threadIdx.x - d] : 0;
        __syncthreads();
        tmp[threadIdx.x] += t;
        __syncthreads();
    }
    if (threadIdx.x < SCAN_GRID) b[threadIdx.x] = tmp[threadIdx.x] - v;  // exclusive
}

// ---------------- pass 3: add block base, emit offs + cursor --------------
__global__ __launch_bounds__(1024) void scan_finalize(
        int* __restrict__ offsM, int* __restrict__ offsW,
        int* __restrict__ curM, int* __restrict__ curW,
        const int* __restrict__ bsums) {
    int* offs = blockIdx.y ? offsW : offsM;
    int* cur  = blockIdx.y ? curW  : curM;
    int g = blockIdx.x * SCAN_B + threadIdx.x;
    if (g < N_NODES) {
        int o = offs[g] + bsums[blockIdx.y * 128 + blockIdx.x];
        offs[g] = o;
        cur[g] = o;
    }
    if (g == 0) offs[N_NODES] = blockIdx.y ? N_WORLD : N_MESH;
}

// ---------------- build permutation (counting-sort placement) -------------
__global__ __launch_bounds__(256) void build_perm(
        const int* __restrict__ dst, int E, int* __restrict__ cursor,
        int* __restrict__ perm) {
    int i = blockIdx.x * 256 + threadIdx.x;
    if (i < E) {
        int slot = atomicAdd(&cursor[dst[i]], 1);
        perm[slot] = i;
    }
}

// ---------------- gather-reduce: agg[n] = mean of attr rows ---------------
__global__ __launch_bounds__(256) void aggregate_kernel(
        const float* __restrict__ attr, const int* __restrict__ perm,
        const int* __restrict__ offs, float* __restrict__ agg) {
    int node = blockIdx.x * 4 + (threadIdx.x >> 6);
    if (node >= N_NODES) return;
    int l = threadIdx.x & 63;
    int beg = offs[node], end = offs[node + 1];
    float sx = 0.f, sy = 0.f;
    int j = beg;
    if (j < end) {
        int e = perm[j];
        float2 v = *reinterpret_cast<const float2*>(&attr[(size_t)e * D + l * 2]);
        for (++j; j < end; ++j) {
            int e2 = perm[j];
            float2 v2 = *reinterpret_cast<const float2*>(&attr[(size_t)e2 * D + l * 2]);
            sx += v.x; sy += v.y;
            v = v2;
        }
        sx += v.x; sy += v.y;
    }
    int c = end - beg;
    float inv = 1.0f / (float)(c > 1 ? c : 1);
    float2 r; r.x = sx * inv; r.y = sy * inv;
    *reinterpret_cast<float2*>(&agg[(size_t)node * D + l * 2]) = r;
}

// ---------------- weight prep: transpose + f32->bf16 ----------------------
__global__ __launch_bounds__(256) void prep_weights(
        const float* __restrict__ W1, const float* __restrict__ W2,
        unsigned short* __restrict__ Wt1, unsigned short* __restrict__ Wt2) {
    int idx = blockIdx.x * 256 + threadIdx.x;
    if (idx < 384 * D) {
        int n = idx / 384, k = idx % 384;
        Wt1[n * 384 + k] = f2bf(W1[k * D + n]);      // Wt1[n][k] = W1[k][n]
    } else if (idx < 384 * D + D * D) {
        int i2 = idx - 384 * D;
        int n = i2 / D, k = i2 % D;
        Wt2[n * D + k] = f2bf(W2[k * D + n]);
    }
}

// ---------------- fused MLP per 64-node tile ------------------------------
__global__ __launch_bounds__(256) void mlp_kernel(
        const float* __restrict__ x,
        const float* __restrict__ mesh_agg, const float* __restrict__ world_agg,
        const unsigned short* __restrict__ Wt1, const unsigned short* __restrict__ Wt2,
        const float* __restrict__ b1, const float* __restrict__ b2,
        const float* __restrict__ gamma, const float* __restrict__ beta,
        float* __restrict__ out) {
    __shared__ __align__(16) short h_lds[BM * LDK];   // 50176 B, reused for h1
    const int tid = threadIdx.x;
    const int block0 = blockIdx.x * BM;

    // ---- Phase A: stage h = [x | mesh_agg | world_agg] as bf16 -----------
    for (int idx = tid; idx < BM * 32; idx += 256) {
        int row = idx >> 5, c4 = (idx & 31) * 4;
        int node = block0 + row;
        float4 v = {0.f, 0.f, 0.f, 0.f};
        if (node < N_NODES) v = *reinterpret_cast<const float4*>(&x[(size_t)node * D + c4]);
        ushort4 pack = {f2bf(v.x), f2bf(v.y), f2bf(v.z), f2bf(v.w)};
        *reinterpret_cast<ushort4*>(&h_lds[row * LDK + c4]) = pack;
    }
    for (int idx = tid; idx < BM * 32; idx += 256) {
        int row = idx >> 5, c4 = (idx & 31) * 4;
        int node = block0 + row;
        float4 v = {0.f, 0.f, 0.f, 0.f};
        if (node < N_NODES) v = *reinterpret_cast<const float4*>(&mesh_agg[(size_t)node * D + c4]);
        ushort4 pack = {f2bf(v.x), f2bf(v.y), f2bf(v.z), f2bf(v.w)};
        *reinterpret_cast<ushort4*>(&h_lds[row * LDK + 128 + c4]) = pack;
    }
    for (int idx = tid; idx < BM * 32; idx += 256) {
        int row = idx >> 5, c4 = (idx & 31) * 4;
        int node = block0 + row;
        float4 v = {0.f, 0.f, 0.f, 0.f};
        if (node < N_NODES) v = *reinterpret_cast<const float4*>(&world_agg[(size_t)node * D + c4]);
        ushort4 pack = {f2bf(v.x), f2bf(v.y), f2bf(v.z), f2bf(v.w)};
        *reinterpret_cast<ushort4*>(&h_lds[row * LDK + 256 + c4]) = pack;
    }
    __syncthreads();

    // ---- Phase B: GEMM1  h[64x384] @ W1[384x128]  (wave w owns 16 rows) --
    const int w = tid >> 6, l = tid & 63;
    const int lm = l & 15, lg = l >> 4;
    f32x4 acc[8];
    #pragma unroll
    for (int nt = 0; nt < 8; nt++) {
        float bv = b1[nt * 16 + lm];
        acc[nt] = (f32x4){bv, bv, bv, bv};
    }
    {
        const short* arow = &h_lds[(w * 16 + lm) * LDK + lg * 8];
        for (int ks = 0; ks < 12; ks++) {
            short8 a = *reinterpret_cast<const short8*>(arow + ks * 32);
            #pragma unroll
            for (int nt = 0; nt < 8; nt++) {
                short8 b = *reinterpret_cast<const short8*>(
                    &Wt1[(size_t)(nt * 16 + lm) * 384 + ks * 32 + lg * 8]);
                acc[nt] = __builtin_amdgcn_mfma_f32_16x16x32_bf16(a, b, acc[nt], 0, 0, 0);
            }
        }
    }
    __syncthreads();   // all waves finished reading h_lds

    // ---- Phase C: ReLU -> bf16 -> h1 in LDS (reuse h_lds) ----------------
    // C/D layout: col = nt*16 + (lane&15), row = (lane>>4)*4 + reg
    #pragma unroll
    for (int nt = 0; nt < 8; nt++) {
        #pragma unroll
        for (int r = 0; r < 4; r++) {
            float v = acc[nt][r] > 0.f ? acc[nt][r] : 0.f;
            int row = w * 16 + lg * 4 + r;
            h_lds[row * LDH + nt * 16 + lm] = (short)f2bf(v);
        }
    }
    __syncthreads();

    // ---- Phase D: GEMM2  h1[64x128] @ W2[128x128] ------------------------
    f32x4 acc2[8];
    #pragma unroll
    for (int nt = 0; nt < 8; nt++) {
        float bv = b2[nt * 16 + lm];
        acc2[nt] = (f32x4){bv, bv, bv, bv};
    }
    {
        const short* a2row = &h_lds[(w * 16 + lm) * LDH + lg * 8];
        for (int ks = 0; ks < 4; ks++) {
            short8 a = *reinterpret_cast<const short8*>(a2row + ks * 32);
            #pragma unroll
            for (int nt = 0; nt < 8; nt++) {
                short8 b = *reinterpret_cast<const short8*>(
                    &Wt2[(size_t)(nt * 16 + lm) * D + ks * 32 + lg * 8]);
                acc2[nt] = __builtin_amdgcn_mfma_f32_16x16x32_bf16(a, b, acc2[nt], 0, 0, 0);
            }
        }
    }

    // ---- Phase E: LayerNorm (in-register, 16-lane reductions) + residual -
    float gam[8], bet[8];
    #pragma unroll
    for (int nt = 0; nt < 8; nt++) {
        gam[nt] = gamma[nt * 16 + lm];
        bet[nt] = beta[nt * 16 + lm];
    }
    #pragma unroll
    for (int r = 0; r < 4; r++) {
        float s = 0.f, ss = 0.f;
        #pragma unroll
        for (int nt = 0; nt < 8; nt++) { float v = acc2[nt][r]; s += v; ss += v * v; }
        #pragma unroll
        for (int m = 1; m < 16; m <<= 1) {
            s  += __shfl_xor(s, m, 64);
            ss += __shfl_xor(ss, m, 64);
        }
        float mean = s * (1.0f / 128.0f);
        float var  = ss * (1.0f / 128.0f) - mean * mean;
        float rstd = rsqrtf(var + 1e-5f);
        int node = block0 + w * 16 + lg * 4 + r;
        if (node < N_NODES) {
            #pragma unroll
            for (int nt = 0; nt < 8; nt++) {
                int col = nt * 16 + lm;
                float v = (acc2[nt][r] - mean) * rstd * gam[nt] + bet[nt];
                out[(size_t)node * D + col] = x[(size_t)node * D + col] + v;
            }
        }
    }
}

extern "C" void kernel_launch(void* const* d_in, const int* in_sizes, int n_in,
                              void* d_out, int out_size, void* d_ws, size_t ws_size,
                              hipStream_t stream) {
    const float* x          = (const float*)d_in[0];
    const float* mesh_attr  = (const float*)d_in[1];
    const float* world_attr = (const float*)d_in[2];
    const int*   mesh_dst   = (const int*)d_in[3];
    const int*   world_dst  = (const int*)d_in[4];
    const float* W1         = (const float*)d_in[5];
    const float* b1         = (const float*)d_in[6];
    const float* W2         = (const float*)d_in[7];
    const float* b2         = (const float*)d_in[8];
    const float* gamma      = (const float*)d_in[9];
    const float* beta       = (const float*)d_in[10];
    float* out = (float*)d_out;

    char* ws = (char*)d_ws;
    size_t off = 0;
    float* world_agg = (float*)(ws + off); off += (size_t)N_NODES * D * 4;   // 51.2 MB
    int* mesh_cnt   = (int*)(ws + off); off += (size_t)N_NODES * 4;
    int* world_cnt  = (int*)(ws + off); off += (size_t)N_NODES * 4;
    int* mesh_cur   = (int*)(ws + off); off += (size_t)N_NODES * 4;
    int* world_cur  = (int*)(ws + off); off += (size_t)N_NODES * 4;
    int* mesh_perm  = (int*)(ws + off); off += (size_t)N_MESH * 4;
    int* world_perm = (int*)(ws + off); off += (size_t)N_WORLD * 4;
    int* mesh_offs  = (int*)(ws + off); off += (size_t)(N_NODES + 1) * 4;
    int* world_offs = (int*)(ws + off); off += (size_t)(N_NODES + 1) * 4;
    int* bsums      = (int*)(ws + off); off += (size_t)256 * 4;   // [2][128]
    off = (off + 15) & ~(size_t)15;
    unsigned short* Wt1 = (unsigned short*)(ws + off); off += (size_t)384 * D * 2;
    unsigned short* Wt2 = (unsigned short*)(ws + off); off += (size_t)D * D * 2;

    // mesh_agg aliases d_out: each MLP block reads its own agg rows (phase A)
    // strictly before writing the same out rows (phase E).
    float* mesh_agg = out;

    zero_counts<<<(2 * N_NODES + 255) / 256, 256, 0, stream>>>(mesh_cnt, 2 * N_NODES);
    hist_kernel<<<(N_MESH  + 255) / 256, 256, 0, stream>>>(mesh_dst,  N_MESH,  mesh_cnt);
    hist_kernel<<<(N_WORLD + 255) / 256, 256, 0, stream>>>(world_dst, N_WORLD, world_cnt);
    {
        dim3 g1(SCAN_GRID, 2);
        scan_local<<<g1, SCAN_B, 0, stream>>>(mesh_cnt, world_cnt, mesh_offs, world_offs, bsums);
        scan_mid<<<2, 128, 0, stream>>>(bsums);
        scan_finalize<<<g1, SCAN_B, 0, stream>>>(mesh_offs, world_offs, mesh_cur, world_cur, bsums);
    }
    build_perm<<<(N_MESH  + 255) / 256, 256, 0, stream>>>(mesh_dst,  N_MESH,  mesh_cur,  mesh_perm);
    build_perm<<<(N_WORLD + 255) / 256, 256, 0, stream>>>(world_dst, N_WORLD, world_cur, world_perm);
    prep_weights<<<(384 * D + D * D + 255) / 256, 256, 0, stream>>>(W1, W2, Wt1, Wt2);
    aggregate_kernel<<<(N_NODES + 3) / 4, 256, 0, stream>>>(mesh_attr,  mesh_perm,  mesh_offs,  mesh_agg);
    aggregate_kernel<<<(N_NODES + 3) / 4, 256, 0, stream>>>(world_attr, world_perm, world_offs, world_agg);
    mlp_kernel<<<(N_NODES + BM - 1) / BM, 256, 0, stream>>>(
        x, mesh_agg, world_agg, Wt1, Wt2, b1, b2, gamma, beta, out);
}

// Round 6
// 341.252 us; speedup vs baseline: 2.4384x; 1.1530x over previous
//
#include <hip/hip_runtime.h>

#define N_NODES 100000
#define D 128
#define N_MESH 600000
#define N_WORLD 300000
#define BM 64          // nodes per block in MLP kernel
#define LDK 392        // padded leading dim of h tile (384 + 8) in bf16 elems
#define LDH 136        // padded leading dim of h1 tile (128 + 8)
#define SCAN_B 1024
#define SCAN_GRID ((N_NODES + SCAN_B - 1) / SCAN_B)   // 98
#define N_WEIGHT (384 * D + D * D)                    // 65536

typedef __attribute__((ext_vector_type(8))) short short8;
typedef __attribute__((ext_vector_type(4))) float f32x4;

// f32 -> bf16 round-to-nearest-even (finite inputs)
__device__ __forceinline__ unsigned short f2bf(float f) {
    unsigned u = __builtin_bit_cast(unsigned, f);
    u += 0x7fffu + ((u >> 16) & 1u);
    return (unsigned short)(u >> 16);
}

// ---------------- fused: weight transpose->bf16 + zero counts -------------
__global__ __launch_bounds__(256) void prep_zero(
        const float* __restrict__ W1, const float* __restrict__ W2,
        unsigned short* __restrict__ Wt1, unsigned short* __restrict__ Wt2,
        int* __restrict__ cnts /* [2*N_NODES] */) {
    int idx = blockIdx.x * 256 + threadIdx.x;
    if (idx < 384 * D) {
        int n = idx / 384, k = idx % 384;
        Wt1[n * 384 + k] = f2bf(W1[k * D + n]);      // Wt1[n][k] = W1[k][n]
    } else if (idx < N_WEIGHT) {
        int i2 = idx - 384 * D;
        int n = i2 / D, k = i2 % D;
        Wt2[n * D + k] = f2bf(W2[k * D + n]);
    } else {
        int i = idx - N_WEIGHT;
        if (i < 2 * N_NODES) cnts[i] = 0;
    }
}

// ---------------- histogram of both dst arrays ----------------------------
__global__ __launch_bounds__(256) void hist_both(
        const int* __restrict__ mdst, const int* __restrict__ wdst,
        int* __restrict__ mcnt, int* __restrict__ wcnt) {
    int i = blockIdx.x * 256 + threadIdx.x;
    if (i < N_MESH) {
        atomicAdd(&mcnt[mdst[i]], 1);
    } else {
        int j = i - N_MESH;
        if (j < N_WORLD) atomicAdd(&wcnt[wdst[j]], 1);
    }
}

// ---------------- multi-block scan, pass 1: per-block exclusive scan ------
__global__ __launch_bounds__(1024) void scan_local(
        const int* __restrict__ cntM, const int* __restrict__ cntW,
        int* __restrict__ offsM, int* __restrict__ offsW,
        int* __restrict__ bsums) {
    const int* cnt = blockIdx.y ? cntW : cntM;
    int* offs = blockIdx.y ? offsW : offsM;
    __shared__ int tmp[SCAN_B];
    int g = blockIdx.x * SCAN_B + threadIdx.x;
    int v = (g < N_NODES) ? cnt[g] : 0;
    tmp[threadIdx.x] = v;
    __syncthreads();
    for (int d = 1; d < SCAN_B; d <<= 1) {
        int t = (threadIdx.x >= d) ? tmp[threadIdx.x - d] : 0;
        __syncthreads();
        tmp[threadIdx.x] += t;
        __syncthreads();
    }
    if (g < N_NODES) offs[g] = tmp[threadIdx.x] - v;   // exclusive within block
    if (threadIdx.x == SCAN_B - 1) bsums[blockIdx.y * 128 + blockIdx.x] = tmp[SCAN_B - 1];
}

// ---------------- pass 2: exclusive scan of block sums (grid=2 blocks) ----
__global__ __launch_bounds__(128) void scan_mid(int* __restrict__ bsums) {
    __shared__ int tmp[128];
    int* b = bsums + blockIdx.x * 128;
    int v = (threadIdx.x < SCAN_GRID) ? b[threadIdx.x] : 0;
    tmp[threadIdx.x] = v;
    __syncthreads();
    for (int d = 1; d < 128; d <<= 1) {
        int t = (threadIdx.x >= d) ? tmp[threadIdx.x - d] : 0;
        __syncthreads();
        tmp[threadIdx.x] += t;
        __syncthreads();
    }
    if (threadIdx.x < SCAN_GRID) b[threadIdx.x] = tmp[threadIdx.x] - v;  // exclusive
}

// ---------------- pass 3: add block base, emit offs + cursor --------------
__global__ __launch_bounds__(1024) void scan_finalize(
        int* __restrict__ offsM, int* __restrict__ offsW,
        int* __restrict__ curM, int* __restrict__ curW,
        const int* __restrict__ bsums) {
    int* offs = blockIdx.y ? offsW : offsM;
    int* cur  = blockIdx.y ? curW  : curM;
    int g = blockIdx.x * SCAN_B + threadIdx.x;
    if (g < N_NODES) {
        int o = offs[g] + bsums[blockIdx.y * 128 + blockIdx.x];
        offs[g] = o;
        cur[g] = o;
    }
    if (g == 0) offs[N_NODES] = blockIdx.y ? N_WORLD : N_MESH;
}

// ---------------- build both permutations (counting-sort placement) -------
__global__ __launch_bounds__(256) void perm_both(
        const int* __restrict__ mdst, const int* __restrict__ wdst,
        int* __restrict__ mcur, int* __restrict__ wcur,
        int* __restrict__ mperm, int* __restrict__ wperm) {
    int i = blockIdx.x * 256 + threadIdx.x;
    if (i < N_MESH) {
        int slot = atomicAdd(&mcur[mdst[i]], 1);
        mperm[slot] = i;
    } else {
        int j = i - N_MESH;
        if (j < N_WORLD) {
            int slot = atomicAdd(&wcur[wdst[j]], 1);
            wperm[slot] = j;
        }
    }
}

// ---------------- gather-reduce both graphs: agg[n] = mean (bf16 out) -----
// 2 nodes per wave: half = lane>>5 picks node, 32 lanes x float4 = 512B row.
// perm entries batch-loaded (1 load per node), broadcast via shfl -> all row
// loads are independent and pipeline under vmcnt.
#define WAVES_PER_TYPE ((N_NODES + 1) / 2)            // 50000
__global__ __launch_bounds__(256) void agg_both(
        const float* __restrict__ mesh_attr, const float* __restrict__ world_attr,
        const int* __restrict__ mperm, const int* __restrict__ wperm,
        const int* __restrict__ moffs, const int* __restrict__ woffs,
        unsigned short* __restrict__ magg, unsigned short* __restrict__ wagg) {
    int wid = blockIdx.x * 4 + (threadIdx.x >> 6);
    const float* attr; const int* perm; const int* offs; unsigned short* agg;
    int t = wid;
    if (wid < WAVES_PER_TYPE) {
        attr = mesh_attr; perm = mperm; offs = moffs; agg = magg;
    } else {
        t -= WAVES_PER_TYPE;
        attr = world_attr; perm = wperm; offs = woffs; agg = wagg;
    }
    const int l = threadIdx.x & 63;
    const int half = l >> 5, li = l & 31;
    const int node = t * 2 + half;                    // < N_NODES (N even)
    const int beg = offs[node], end = offs[node + 1];
    const int cnt = end - beg;
    // batch perm load: lane li holds perm[beg+li] for its half's node
    int myperm = (li < cnt) ? perm[beg + li] : 0;
    int n32 = cnt < 32 ? cnt : 32;
    int nother = __shfl_xor(n32, 32, 64);
    int nmax = n32 > nother ? n32 : nother;
    f32x4 s = {0.f, 0.f, 0.f, 0.f};
    for (int j = 0; j < nmax; j++) {
        int e = __shfl(myperm, half * 32 + j, 64);    // all 64 lanes active
        const f32x4* p = reinterpret_cast<const f32x4*>(&attr[(size_t)e * D + li * 4]);
        f32x4 v = __builtin_nontemporal_load(p);
        if (j < n32) s += v;
    }
    for (int j = 32; j < cnt; j++) {                  // rare tail (deg > 32)
        int e = perm[beg + j];
        const f32x4* p = reinterpret_cast<const f32x4*>(&attr[(size_t)e * D + li * 4]);
        f32x4 v = __builtin_nontemporal_load(p);
        s += v;
    }
    float inv = 1.0f / (float)(cnt > 1 ? cnt : 1);
    ushort4 r = {f2bf(s.x * inv), f2bf(s.y * inv), f2bf(s.z * inv), f2bf(s.w * inv)};
    *reinterpret_cast<ushort4*>(&agg[(size_t)node * D + li * 4]) = r;
}

// ---------------- fused MLP per 64-node tile ------------------------------
__global__ __launch_bounds__(256) void mlp_kernel(
        const float* __restrict__ x,
        const unsigned short* __restrict__ mesh_agg, const unsigned short* __restrict__ world_agg,
        const unsigned short* __restrict__ Wt1, const unsigned short* __restrict__ Wt2,
        const float* __restrict__ b1, const float* __restrict__ b2,
        const float* __restrict__ gamma, const float* __restrict__ beta,
        float* __restrict__ out) {
    __shared__ __align__(16) short h_lds[BM * LDK];   // 50176 B, reused for h1
    const int tid = threadIdx.x;
    const int block0 = blockIdx.x * BM;

    // ---- Phase A: stage h = [x | mesh_agg | world_agg] as bf16 -----------
    for (int idx = tid; idx < BM * 32; idx += 256) {
        int row = idx >> 5, c4 = (idx & 31) * 4;
        int node = block0 + row;
        float4 v = {0.f, 0.f, 0.f, 0.f};
        if (node < N_NODES) v = *reinterpret_cast<const float4*>(&x[(size_t)node * D + c4]);
        ushort4 pack = {f2bf(v.x), f2bf(v.y), f2bf(v.z), f2bf(v.w)};
        *reinterpret_cast<ushort4*>(&h_lds[row * LDK + c4]) = pack;
    }
    // agg parts are already bf16: straight vector copies
    for (int idx = tid; idx < BM * 16; idx += 256) {
        int row = idx >> 4, c8 = (idx & 15) * 8;
        int node = block0 + row;
        ushort4 a = {0, 0, 0, 0}, b = {0, 0, 0, 0};
        if (node < N_NODES) {
            a = *reinterpret_cast<const ushort4*>(&mesh_agg[(size_t)node * D + c8]);
            b = *reinterpret_cast<const ushort4*>(&mesh_agg[(size_t)node * D + c8 + 4]);
        }
        *reinterpret_cast<ushort4*>(&h_lds[row * LDK + 128 + c8]) = a;
        *reinterpret_cast<ushort4*>(&h_lds[row * LDK + 128 + c8 + 4]) = b;
    }
    for (int idx = tid; idx < BM * 16; idx += 256) {
        int row = idx >> 4, c8 = (idx & 15) * 8;
        int node = block0 + row;
        ushort4 a = {0, 0, 0, 0}, b = {0, 0, 0, 0};
        if (node < N_NODES) {
            a = *reinterpret_cast<const ushort4*>(&world_agg[(size_t)node * D + c8]);
            b = *reinterpret_cast<const ushort4*>(&world_agg[(size_t)node * D + c8 + 4]);
        }
        *reinterpret_cast<ushort4*>(&h_lds[row * LDK + 256 + c8]) = a;
        *reinterpret_cast<ushort4*>(&h_lds[row * LDK + 256 + c8 + 4]) = b;
    }
    __syncthreads();

    // ---- Phase B: GEMM1  h[64x384] @ W1[384x128]  (wave w owns 16 rows) --
    const int w = tid >> 6, l = tid & 63;
    const int lm = l & 15, lg = l >> 4;
    f32x4 acc[8];
    #pragma unroll
    for (int nt = 0; nt < 8; nt++) {
        float bv = b1[nt * 16 + lm];
        acc[nt] = (f32x4){bv, bv, bv, bv};
    }
    {
        const short* arow = &h_lds[(w * 16 + lm) * LDK + lg * 8];
        for (int ks = 0; ks < 12; ks++) {
            short8 a = *reinterpret_cast<const short8*>(arow + ks * 32);
            #pragma unroll
            for (int nt = 0; nt < 8; nt++) {
                short8 b = *reinterpret_cast<const short8*>(
                    &Wt1[(size_t)(nt * 16 + lm) * 384 + ks * 32 + lg * 8]);
                acc[nt] = __builtin_amdgcn_mfma_f32_16x16x32_bf16(a, b, acc[nt], 0, 0, 0);
            }
        }
    }
    __syncthreads();   // all waves finished reading h_lds

    // ---- Phase C: ReLU -> bf16 -> h1 in LDS (reuse h_lds) ----------------
    // C/D layout: col = nt*16 + (lane&15), row = (lane>>4)*4 + reg
    #pragma unroll
    for (int nt = 0; nt < 8; nt++) {
        #pragma unroll
        for (int r = 0; r < 4; r++) {
            float v = acc[nt][r] > 0.f ? acc[nt][r] : 0.f;
            int row = w * 16 + lg * 4 + r;
            h_lds[row * LDH + nt * 16 + lm] = (short)f2bf(v);
        }
    }
    __syncthreads();

    // ---- Phase D: GEMM2  h1[64x128] @ W2[128x128] ------------------------
    f32x4 acc2[8];
    #pragma unroll
    for (int nt = 0; nt < 8; nt++) {
        float bv = b2[nt * 16 + lm];
        acc2[nt] = (f32x4){bv, bv, bv, bv};
    }
    {
        const short* a2row = &h_lds[(w * 16 + lm) * LDH + lg * 8];
        for (int ks = 0; ks < 4; ks++) {
            short8 a = *reinterpret_cast<const short8*>(a2row + ks * 32);
            #pragma unroll
            for (int nt = 0; nt < 8; nt++) {
                short8 b = *reinterpret_cast<const short8*>(
                    &Wt2[(size_t)(nt * 16 + lm) * D + ks * 32 + lg * 8]);
                acc2[nt] = __builtin_amdgcn_mfma_f32_16x16x32_bf16(a, b, acc2[nt], 0, 0, 0);
            }
        }
    }

    // ---- Phase E: LayerNorm (in-register, 16-lane reductions) + residual -
    float gam[8], bet[8];
    #pragma unroll
    for (int nt = 0; nt < 8; nt++) {
        gam[nt] = gamma[nt * 16 + lm];
        bet[nt] = beta[nt * 16 + lm];
    }
    #pragma unroll
    for (int r = 0; r < 4; r++) {
        float s = 0.f, ss = 0.f;
        #pragma unroll
        for (int nt = 0; nt < 8; nt++) { float v = acc2[nt][r]; s += v; ss += v * v; }
        #pragma unroll
        for (int m = 1; m < 16; m <<= 1) {
            s  += __shfl_xor(s, m, 64);
            ss += __shfl_xor(ss, m, 64);
        }
        float mean = s * (1.0f / 128.0f);
        float var  = ss * (1.0f / 128.0f) - mean * mean;
        float rstd = rsqrtf(var + 1e-5f);
        int node = block0 + w * 16 + lg * 4 + r;
        if (node < N_NODES) {
            #pragma unroll
            for (int nt = 0; nt < 8; nt++) {
                int col = nt * 16 + lm;
                float v = (acc2[nt][r] - mean) * rstd * gam[nt] + bet[nt];
                out[(size_t)node * D + col] = x[(size_t)node * D + col] + v;
            }
        }
    }
}

extern "C" void kernel_launch(void* const* d_in, const int* in_sizes, int n_in,
                              void* d_out, int out_size, void* d_ws, size_t ws_size,
                              hipStream_t stream) {
    const float* x          = (const float*)d_in[0];
    const float* mesh_attr  = (const float*)d_in[1];
    const float* world_attr = (const float*)d_in[2];
    const int*   mesh_dst   = (const int*)d_in[3];
    const int*   world_dst  = (const int*)d_in[4];
    const float* W1         = (const float*)d_in[5];
    const float* b1         = (const float*)d_in[6];
    const float* W2         = (const float*)d_in[7];
    const float* b2         = (const float*)d_in[8];
    const float* gamma      = (const float*)d_in[9];
    const float* beta       = (const float*)d_in[10];
    float* out = (float*)d_out;

    char* ws = (char*)d_ws;
    size_t off = 0;
    unsigned short* magg = (unsigned short*)(ws + off); off += (size_t)N_NODES * D * 2;  // 25.6 MB
    unsigned short* wagg = (unsigned short*)(ws + off); off += (size_t)N_NODES * D * 2;  // 25.6 MB
    int* mesh_cnt   = (int*)(ws + off); off += (size_t)N_NODES * 4;
    int* world_cnt  = (int*)(ws + off); off += (size_t)N_NODES * 4;   // contiguous after mesh_cnt
    int* mesh_cur   = (int*)(ws + off); off += (size_t)N_NODES * 4;
    int* world_cur  = (int*)(ws + off); off += (size_t)N_NODES * 4;
    int* mesh_perm  = (int*)(ws + off); off += (size_t)N_MESH * 4;
    int* world_perm = (int*)(ws + off); off += (size_t)N_WORLD * 4;
    int* mesh_offs  = (int*)(ws + off); off += (size_t)(N_NODES + 1) * 4;
    int* world_offs = (int*)(ws + off); off += (size_t)(N_NODES + 1) * 4;
    int* bsums      = (int*)(ws + off); off += (size_t)256 * 4;   // [2][128]
    off = (off + 15) & ~(size_t)15;
    unsigned short* Wt1 = (unsigned short*)(ws + off); off += (size_t)384 * D * 2;
    unsigned short* Wt2 = (unsigned short*)(ws + off); off += (size_t)D * D * 2;

    prep_zero<<<(N_WEIGHT + 2 * N_NODES + 255) / 256, 256, 0, stream>>>(
        W1, W2, Wt1, Wt2, mesh_cnt);
    hist_both<<<(N_MESH + N_WORLD + 255) / 256, 256, 0, stream>>>(
        mesh_dst, world_dst, mesh_cnt, world_cnt);
    {
        dim3 g1(SCAN_GRID, 2);
        scan_local<<<g1, SCAN_B, 0, stream>>>(mesh_cnt, world_cnt, mesh_offs, world_offs, bsums);
        scan_mid<<<2, 128, 0, stream>>>(bsums);
        scan_finalize<<<g1, SCAN_B, 0, stream>>>(mesh_offs, world_offs, mesh_cur, world_cur, bsums);
    }
    perm_both<<<(N_MESH + N_WORLD + 255) / 256, 256, 0, stream>>>(
        mesh_dst, world_dst, mesh_cur, world_cur, mesh_perm, world_perm);
    agg_both<<<(2 * WAVES_PER_TYPE + 3) / 4, 256, 0, stream>>>(
        mesh_attr, world_attr, mesh_perm, world_perm, mesh_offs, world_offs, magg, wagg);
    mlp_kernel<<<(N_NODES + BM - 1) / BM, 256, 0, stream>>>(
        x, magg, wagg, Wt1, Wt2, b1, b2, gamma, beta, out);
}